// Round 8
// baseline (27.746 us; speedup 1.0000x reference)
//
#include <hip/hip_runtime.h>
#include <hip/hip_fp16.h>
#include <math.h>

#define FEAT 64

// clang-native vector types: accepted by __builtin_nontemporal_{load,store}
typedef float fx4 __attribute__((ext_vector_type(4)));
typedef int   ix4 __attribute__((ext_vector_type(4)));
typedef unsigned int ux4 __attribute__((ext_vector_type(4)));

// ---- pass A: node_value f32 -> f16 table in workspace (streaming) ----
__global__ __launch_bounds__(256) void convert_f32_to_f16_kernel(
    const fx4* __restrict__ src4,
    uint2* __restrict__ dst2,
    int n4)
{
    const int i = blockIdx.x * blockDim.x + threadIdx.x;
    if (i >= n4) return;
    const fx4 v = __builtin_nontemporal_load(&src4[i]);   // pure stream
    const __half2 h0 = __floats2half2_rn(v.x, v.y);
    const __half2 h1 = __floats2half2_rn(v.z, v.w);
    uint2 o;
    o.x = *reinterpret_cast<const unsigned int*>(&h0);
    o.y = *reinterpret_cast<const unsigned int*>(&h1);
    dst2[i] = o;
}

// ---- pass B: softmax + weighted gather-aggregate (8 lanes per node) ----
// Streaming accesses (scores, cols, output) are NON-TEMPORAL so they don't
// evict the fp16 gather table from the per-XCD L2. Gathers stay cached.
__global__ __launch_bounds__(256) void gat_softmax_agg_kernel(
    const int* __restrict__ row_ptr,
    const int* __restrict__ col_idx,
    const float* __restrict__ edge_scores,
    const uint4* __restrict__ nv16,    // fp16 table, 8 uint4 per node row
    float* __restrict__ out,           // f32 out, FEAT floats per node row
    int n_nodes)
{
    const int tid  = blockIdx.x * blockDim.x + threadIdx.x;
    const int node = tid >> 3;
    const int sub  = threadIdx.x & 7;
    if (node >= n_nodes) return;

    const int start = row_ptr[node];
    const int end   = row_ptr[node + 1];
    const int deg   = end - start;

    fx4 accA = (fx4)0.f;   // features 8*sub+0..3
    fx4 accB = (fx4)0.f;   // features 8*sub+4..7

    if (deg == 16 && (start & 3) == 0) {
        // 16 scores into registers (group-uniform addresses -> broadcast)
        float s[16];
        {
            const fx4* s4 = (const fx4*)(edge_scores + start);
            #pragma unroll
            for (int i = 0; i < 4; ++i) {
                const fx4 sv = __builtin_nontemporal_load(&s4[i]);
                s[4*i+0] = sv.x; s[4*i+1] = sv.y; s[4*i+2] = sv.z; s[4*i+3] = sv.w;
            }
        }

        // in-register softmax; exp computed once, stored back into s[]
        float m = s[0];
        #pragma unroll
        for (int k = 1; k < 16; ++k) m = fmaxf(m, s[k]);
        float ssum = 0.f;
        #pragma unroll
        for (int k = 0; k < 16; ++k) { s[k] = __expf(s[k] - m); ssum += s[k]; }
        const float inv = 1.0f / ssum;

        // issue all 16 gathers (16B each, CACHED); col regs die into loads
        uint4 r[16];
        {
            const ix4* c4 = (const ix4*)(col_idx + start);
            #pragma unroll
            for (int i = 0; i < 4; ++i) {
                const ix4 cv = __builtin_nontemporal_load(&c4[i]);
                r[4*i+0] = nv16[(unsigned)cv.x * 8u + sub];
                r[4*i+1] = nv16[(unsigned)cv.y * 8u + sub];
                r[4*i+2] = nv16[(unsigned)cv.z * 8u + sub];
                r[4*i+3] = nv16[(unsigned)cv.w * 8u + sub];
            }
        }

        // consume: fp16 -> f32 FMA, weight = s[k]*inv
        #pragma unroll
        for (int k = 0; k < 16; ++k) {
            const float w = s[k] * inv;
            const __half2 h0 = *reinterpret_cast<const __half2*>(&r[k].x);
            const __half2 h1 = *reinterpret_cast<const __half2*>(&r[k].y);
            const __half2 h2 = *reinterpret_cast<const __half2*>(&r[k].z);
            const __half2 h3 = *reinterpret_cast<const __half2*>(&r[k].w);
            const float2 f0 = __half22float2(h0);
            const float2 f1 = __half22float2(h1);
            const float2 f2 = __half22float2(h2);
            const float2 f3 = __half22float2(h3);
            accA.x = fmaf(w, f0.x, accA.x);
            accA.y = fmaf(w, f0.y, accA.y);
            accA.z = fmaf(w, f1.x, accA.z);
            accA.w = fmaf(w, f1.y, accA.w);
            accB.x = fmaf(w, f2.x, accB.x);
            accB.y = fmaf(w, f2.y, accB.y);
            accB.z = fmaf(w, f3.x, accB.z);
            accB.w = fmaf(w, f3.y, accB.w);
        }
    } else if (deg > 0) {
        // general-degree fallback: serial, scalar, still pure
        float m = -INFINITY;
        for (int e = start; e < end; ++e) m = fmaxf(m, edge_scores[e]);
        float ssum = 0.f;
        for (int e = start; e < end; ++e) ssum += __expf(edge_scores[e] - m);
        const float inv = 1.0f / ssum;
        for (int e = start; e < end; ++e) {
            const float w = __expf(edge_scores[e] - m) * inv;
            const uint4 raw = nv16[(unsigned)col_idx[e] * 8u + sub];
            const __half2 h0 = *reinterpret_cast<const __half2*>(&raw.x);
            const __half2 h1 = *reinterpret_cast<const __half2*>(&raw.y);
            const __half2 h2 = *reinterpret_cast<const __half2*>(&raw.z);
            const __half2 h3 = *reinterpret_cast<const __half2*>(&raw.w);
            const float2 f0 = __half22float2(h0);
            const float2 f1 = __half22float2(h1);
            const float2 f2 = __half22float2(h2);
            const float2 f3 = __half22float2(h3);
            accA.x = fmaf(w, f0.x, accA.x);
            accA.y = fmaf(w, f0.y, accA.y);
            accA.z = fmaf(w, f1.x, accA.z);
            accA.w = fmaf(w, f1.y, accA.w);
            accB.x = fmaf(w, f2.x, accB.x);
            accB.y = fmaf(w, f2.y, accB.y);
            accB.z = fmaf(w, f3.x, accB.z);
            accB.w = fmaf(w, f3.y, accB.w);
        }
    }

    // non-temporal output stores: don't let 12.8MB of writes churn the L2
    fx4* o4 = (fx4*)(out + (long)node * FEAT + 8 * sub);
    __builtin_nontemporal_store(accA, &o4[0]);
    __builtin_nontemporal_store(accB, &o4[1]);
}

extern "C" void kernel_launch(void* const* d_in, const int* in_sizes, int n_in,
                              void* d_out, int out_size, void* d_ws, size_t ws_size,
                              hipStream_t stream) {
    const int*    row_ptr     = (const int*)d_in[0];
    const int*    col_idx     = (const int*)d_in[1];
    const float*  edge_scores = (const float*)d_in[2];
    const float*  node_value  = (const float*)d_in[3];
    float*        out         = (float*)d_out;

    const int n_nodes = in_sizes[0] - 1;
    const int n_feat_total = in_sizes[3];          // n_nodes * FEAT floats

    uint4* nv16 = (uint4*)d_ws;                    // 6.4 MB in workspace

    // pass A: convert node_value to fp16
    {
        const int n4 = n_feat_total / 4;
        const int block = 256;
        const int grid = (n4 + block - 1) / block;
        convert_f32_to_f16_kernel<<<grid, block, 0, stream>>>(
            (const fx4*)node_value, (uint2*)nv16, n4);
    }

    // pass B: softmax + aggregate (8 threads per node)
    {
        const int block = 256;                     // 32 nodes per block
        const long threads_total = (long)n_nodes * 8;
        const int grid = (int)((threads_total + block - 1) / block);
        gat_softmax_agg_kernel<<<grid, block, 0, stream>>>(
            row_ptr, col_idx, edge_scores, nv16, out, n_nodes);
    }
}